// Round 13
// baseline (37.478 us; speedup 1.0000x reference)
//
#include <hip/hip_runtime.h>

#define BATCH    16384
#define NF       1024
#define NWAVES1  8192   // phase 1: 2048 blocks x 4 waves
#define NWAVES2  4096   // phase 2: 1024 blocks x 4 waves

// QUARTER-SPLIT HIGH-OCCUPANCY STRUCTURE (R12 diagnosis: even a tail-free
// streamer runs 2.6 TB/s at 8 waves/CU; every prior round was wave-starved;
// m13's 6.3 TB/s copy runs 32 waves/CU).
// Phase 1: each wave owns ONE QUARTER (256 features) of rows' dot products.
//   Pinned W slice = 10 x float4 = 40 VGPR; live set ~61 -> fits the
//   64-VGPR cap of __launch_bounds__(256,4) (R7's empirical cap, now used
//   deliberately) -> 8 waves/SIMD = 32 waves/CU. 2048 blocks; block's 4
//   waves = 4 quarters of the same row stream.
//   Per row: 1 float4 load, 40 FMA, per-d 16-group DPP reduce + 2 shfl_xor,
//   lane0 stores z_quarter to part[row][d][q] (2.6 MB, R12-proven size).
// Phase 2: R12's proven combine (+bias here), leaf DP, out.

template <int CTRL>
__device__ __forceinline__ float dpp_add(float x) {
    int xi = __builtin_bit_cast(int, x);
    int yi = __builtin_amdgcn_update_dpp(xi, xi, CTRL, 0xf, 0xf, false);
    return x + __builtin_bit_cast(float, yi);
}

// sum over each 16-lane group (result in every lane of the group)
__device__ __forceinline__ float group16_reduce(float x) {
    x = dpp_add<0xB1>(x);    // quad_perm [1,0,3,2]
    x = dpp_add<0x4E>(x);    // quad_perm [2,3,0,1] -> quad sums
    x = dpp_add<0x124>(x);   // row_ror:4
    x = dpp_add<0x128>(x);   // row_ror:8 -> 16-lane group sum
    return x;
}

__device__ __forceinline__ float wave_sum(float x) {
    float r = group16_reduce(x);
    int ri = __builtin_bit_cast(int, r);
    float s0 = __builtin_bit_cast(float, __builtin_amdgcn_readlane(ri, 0));
    float s1 = __builtin_bit_cast(float, __builtin_amdgcn_readlane(ri, 16));
    float s2 = __builtin_bit_cast(float, __builtin_amdgcn_readlane(ri, 32));
    float s3 = __builtin_bit_cast(float, __builtin_amdgcn_readlane(ri, 48));
    return (s0 + s1) + (s2 + s3);
}

// ---------------- phase 1: quarter logits, 32 waves/CU ----------------
__global__ __launch_bounds__(256, 4)
void sdt_logits(const float* __restrict__ x,
                const float* __restrict__ W,
                float* __restrict__ part)   // [BATCH][10][4]
{
    const int lane = threadIdx.x & 63;
    const int wg   = (int)((blockIdx.x * blockDim.x + threadIdx.x) >> 6);
    const int q    = wg & 3;          // quarter index
    const int rseq = wg >> 2;         // row stream 0..2047

    // ---- pinned W quarter-slices: Wr[d] = W[d][q*256 + 4l .. +3] ----
    float4 Wr[10];
#pragma unroll
    for (int d = 0; d < 10; ++d)
        Wr[d] = *reinterpret_cast<const float4*>(W + d * NF + q * 256 + 4 * lane);
#pragma unroll
    for (int d = 0; d < 10; ++d)
        asm volatile("" : "+v"(Wr[d].x), "+v"(Wr[d].y),
                          "+v"(Wr[d].z), "+v"(Wr[d].w));

    const float* xq = x + q * 256 + 4 * lane;

    for (int i = 0; i < 8; ++i) {
        const int row = rseq + i * 2048;

        const float4 xv = *reinterpret_cast<const float4*>(xq + (size_t)row * NF);

        // 10 quarter-dots (4 FMA each) -> reduce -> lane0 store
        float* pr = part + (size_t)row * 40 + q;
#pragma unroll
        for (int d = 0; d < 10; ++d) {
            float a = xv.x * Wr[d].x;
            a = fmaf(xv.y, Wr[d].y, a);
            a = fmaf(xv.z, Wr[d].z, a);
            a = fmaf(xv.w, Wr[d].w, a);
            float r = group16_reduce(a);
            r += __shfl_xor(r, 16, 64);
            r += __shfl_xor(r, 32, 64);
            if (lane == 0) pr[d * 4] = r;
        }
    }
}

// ---------------- phase 2: combine -> sigmoid -> leaf DP -> out ----------------
__global__ __launch_bounds__(256, 2)
void sdt_combine(const float* __restrict__ part,
                 const float* __restrict__ b,
                 const float* __restrict__ leaf,
                 float* __restrict__ out)
{
    const int lane = threadIdx.x & 63;
    const int wid  = (int)((blockIdx.x * blockDim.x + threadIdx.x) >> 6);

    // leaf table, transposed: lv_t[i*64 + l] = leaf[l*16 + i]
    __shared__ float lv_t[1024];
#pragma unroll
    for (int e = 0; e < 4; ++e) {
        int idx = threadIdx.x * 4 + e;
        lv_t[idx] = leaf[(idx & 63) * 16 + (idx >> 6)];
    }

    float bias[10];
#pragma unroll
    for (int d = 0; d < 10; ++d) bias[d] = b[d];

    __syncthreads();

    for (int row = wid; row < BATCH; row += NWAVES2) {
        // 40 partials, coalesced (lanes 0..39); z_d = sum of quad 4d..4d+3
        float p = 0.0f;
        if (lane < 40) p = part[(size_t)row * 40 + lane];
        p = dpp_add<0xB1>(p);
        p = dpp_add<0x4E>(p);   // quad sums: z_d complete in lanes 4d..4d+3

        int pi = __builtin_bit_cast(int, p);
        float g[10];
#pragma unroll
        for (int d = 0; d < 10; ++d) {
            float z = __builtin_bit_cast(float, __builtin_amdgcn_readlane(pi, 4 * d))
                      + bias[d];
            g[d] = __builtin_amdgcn_rcpf(1.0f + __expf(-z));
        }

        // leaf DP: contract LSB (depth 9) upward
        float s9[8];
#pragma unroll
        for (int j = 0; j < 8; ++j) {
            float La = lv_t[(2 * j) * 64 + lane];
            float Lb = lv_t[(2 * j + 1) * 64 + lane];
            s9[j] = fmaf(g[9], Lb - La, La);
        }
        float s8[4];
#pragma unroll
        for (int j = 0; j < 4; ++j)
            s8[j] = fmaf(g[8], s9[2 * j + 1] - s9[2 * j], s9[2 * j]);
        float s7[2];
#pragma unroll
        for (int j = 0; j < 2; ++j)
            s7[j] = fmaf(g[7], s8[2 * j + 1] - s8[2 * j], s8[2 * j]);
        float s6 = fmaf(g[6], s7[1] - s7[0], s7[0]);

        float w = 1.0f;
#pragma unroll
        for (int d = 0; d < 6; ++d) {
            int bit = (lane >> (5 - d)) & 1;
            w *= bit ? g[d] : (1.0f - g[d]);
        }

        float v = wave_sum(w * s6);
        if (lane == 0) out[row] = v;
    }
}

extern "C" void kernel_launch(void* const* d_in, const int* in_sizes, int n_in,
                              void* d_out, int out_size, void* d_ws, size_t ws_size,
                              hipStream_t stream) {
    const float* x    = (const float*)d_in[0];
    const float* W    = (const float*)d_in[1];
    const float* b    = (const float*)d_in[2];
    const float* leaf = (const float*)d_in[3];
    float* out  = (float*)d_out;
    float* part = (float*)d_ws;   // 16384 * 40 * 4 B = 2.62 MB

    sdt_logits<<<2048, 256, 0, stream>>>(x, W, part);
    sdt_combine<<<1024, 256, 0, stream>>>(part, b, leaf, out);
}

// Round 14
// 29.144 us; speedup vs baseline: 1.2860x; 1.2860x over previous
//
#include <hip/hip_runtime.h>

#define BATCH   16384
#define NF      1024

// MAX-MLP STRUCTURE (R14). Diagnosis: reads cap at 2.6 TB/s in every prior
// structure while the harness fill kernel WRITES at 6.8 TB/s at 8% occupancy
// -> reads are in-flight-bytes limited; no prior round ever had >4KB of
// loads outstanding per wave. Here each wave owns 4 consecutive rows and
// issues ALL 16 float4 loads before consuming (16KB/wave in flight,
// k-major order so chunk k consumption waits only vmcnt(12)).
// 16 waves/CU -> 256 KB in flight per CU (4-8x every prior round).
// W in LDS (40KB), each fragment ds_read once per 4 rows (16 FMA / b128).
// 4096 waves exactly = BATCH/4: no loop, no tail. Tails unchanged from R6.

template <int CTRL>
__device__ __forceinline__ float dpp_add(float x) {
    int xi = __builtin_bit_cast(int, x);
    int yi = __builtin_amdgcn_update_dpp(xi, xi, CTRL, 0xf, 0xf, false);
    return x + __builtin_bit_cast(float, yi);
}

__device__ __forceinline__ float row_reduce_dpp(float x) {
    x = dpp_add<0xB1>(x);    // quad_perm [1,0,3,2]
    x = dpp_add<0x4E>(x);    // quad_perm [2,3,0,1] -> quad sums
    x = dpp_add<0x124>(x);   // row_ror:4
    x = dpp_add<0x128>(x);   // row_ror:8 -> 16-lane group sum in every lane
    return x;
}

__device__ __forceinline__ float wave_sum(float x) {
    float r = row_reduce_dpp(x);
    int ri = __builtin_bit_cast(int, r);
    float s0 = __builtin_bit_cast(float, __builtin_amdgcn_readlane(ri, 0));
    float s1 = __builtin_bit_cast(float, __builtin_amdgcn_readlane(ri, 16));
    float s2 = __builtin_bit_cast(float, __builtin_amdgcn_readlane(ri, 32));
    float s3 = __builtin_bit_cast(float, __builtin_amdgcn_readlane(ri, 48));
    return (s0 + s1) + (s2 + s3);
}

__global__ __launch_bounds__(512, 2)
void sdt_kernel(const float* __restrict__ x,
                const float* __restrict__ W,
                const float* __restrict__ b,
                const float* __restrict__ leaf,
                float* __restrict__ out)
{
    const int lane = threadIdx.x & 63;
    const int wid  = (int)(blockIdx.x) * 8 + (int)(threadIdx.x >> 6);

    __shared__ float Ws[10 * NF];    // 40 KB
    __shared__ float lv_t[1024];     // 4 KB, transposed leaf table

    for (int i = threadIdx.x; i < 10 * NF / 4; i += 512)
        reinterpret_cast<float4*>(Ws)[i] = reinterpret_cast<const float4*>(W)[i];

    if (threadIdx.x < 256) {
#pragma unroll
        for (int e = 0; e < 4; ++e) {
            int idx = threadIdx.x * 4 + e;
            lv_t[idx] = leaf[(idx & 63) * 16 + (idx >> 6)];
        }
    }

    float bias[10];
#pragma unroll
    for (int d = 0; d < 10; ++d) bias[d] = b[d];

    __syncthreads();

    // ---- 4 consecutive rows per wave; ALL 16 loads issued upfront,
    //      k-major so chunk-k consumption waits only on 4 oldest loads ----
    const int row0 = wid * 4;
    const float* xr = x + (size_t)row0 * NF + 4 * lane;

    float4 xv[4][4];   // xv[k][r]
#pragma unroll
    for (int k = 0; k < 4; ++k)
#pragma unroll
        for (int r = 0; r < 4; ++r)
            xv[k][r] = *reinterpret_cast<const float4*>(xr + r * NF + k * 256);

    // ---- dots: one W fragment feeds 4 rows (16 FMA per ds_read_b128) ----
    float acc[4][10];
#pragma unroll
    for (int r = 0; r < 4; ++r)
#pragma unroll
        for (int d = 0; d < 10; ++d) acc[r][d] = 0.0f;

#pragma unroll
    for (int k = 0; k < 4; ++k) {
#pragma unroll
        for (int d = 0; d < 10; ++d) {
            const float4 wv = *reinterpret_cast<const float4*>(
                &Ws[d * NF + k * 256 + 4 * lane]);
#pragma unroll
            for (int r = 0; r < 4; ++r) {
                acc[r][d] = fmaf(xv[k][r].x, wv.x, acc[r][d]);
                acc[r][d] = fmaf(xv[k][r].y, wv.y, acc[r][d]);
                acc[r][d] = fmaf(xv[k][r].z, wv.z, acc[r][d]);
                acc[r][d] = fmaf(xv[k][r].w, wv.w, acc[r][d]);
            }
        }
    }

    // ---- per row: reduce -> gates -> leaf DP -> path weight -> store ----
#pragma unroll
    for (int r = 0; r < 4; ++r) {
        float g[10];
#pragma unroll
        for (int d = 0; d < 10; ++d) {
            float z = wave_sum(acc[r][d]) + bias[d];
            g[d] = __builtin_amdgcn_rcpf(1.0f + __expf(-z));
        }

        float s9[8];
#pragma unroll
        for (int j = 0; j < 8; ++j) {
            float La = lv_t[(2 * j) * 64 + lane];
            float Lb = lv_t[(2 * j + 1) * 64 + lane];
            s9[j] = fmaf(g[9], Lb - La, La);
        }
        float s8[4];
#pragma unroll
        for (int j = 0; j < 4; ++j)
            s8[j] = fmaf(g[8], s9[2 * j + 1] - s9[2 * j], s9[2 * j]);
        float s7[2];
#pragma unroll
        for (int j = 0; j < 2; ++j)
            s7[j] = fmaf(g[7], s8[2 * j + 1] - s8[2 * j], s8[2 * j]);
        float s6 = fmaf(g[6], s7[1] - s7[0], s7[0]);

        float w = 1.0f;
#pragma unroll
        for (int d = 0; d < 6; ++d) {
            int bit = (lane >> (5 - d)) & 1;
            w *= bit ? g[d] : (1.0f - g[d]);
        }

        float v = wave_sum(w * s6);
        if (lane == 0) out[row0 + r] = v;
    }
}

extern "C" void kernel_launch(void* const* d_in, const int* in_sizes, int n_in,
                              void* d_out, int out_size, void* d_ws, size_t ws_size,
                              hipStream_t stream) {
    const float* x    = (const float*)d_in[0];
    const float* W    = (const float*)d_in[1];
    const float* b    = (const float*)d_in[2];
    const float* leaf = (const float*)d_in[3];
    float* out = (float*)d_out;

    // 512 blocks x 8 waves x 4 rows = 16384 rows exactly.
    // 2 blocks/CU (44KB LDS, ~120 VGPR) = 16 waves/CU.
    sdt_kernel<<<512, 512, 0, stream>>>(x, W, b, leaf, out);
}